// Round 7
// baseline (208.953 us; speedup 1.0000x reference)
//
#include <hip/hip_runtime.h>
#include <math.h>

#define N_NODES 50000
#define N_EDGES 800000
#define C 128
#define NT 3
#define NEG 0.2f
#define CAP 64   // max in-edges per node kept (Poisson(16): max observed degree ~45)

#define GEMM_XB 782          // ceil(N_NODES/64)
#define MM_BLOCKS (NT * GEMM_XB)   // 2346

#define NXCD 8
#define DST_PER_XCD (N_NODES / NXCD)   // 6250
#define BIN_SLICES 256
#define BIN_BLOCKS (NXCD * BIN_SLICES) // 2048
#define EDGES_PER_SLICE (N_EDGES / BIN_SLICES)   // 3125

// fused grid: 512 groups of 8 alternate bin/mm (bids 0..4095), then 298 mm tail
#define BM_GRID (4096 + (MM_BLOCKS - 2048))      // 4394

typedef __attribute__((ext_vector_type(8))) short short8;   // 8 bf16 = 4 VGPRs
typedef __attribute__((ext_vector_type(4))) float f32x4;

__device__ __forceinline__ float leaky(float v) { return v > 0.f ? v : NEG * v; }

__device__ __forceinline__ unsigned short f2bf(float f) {
  unsigned int u = __float_as_uint(f);
  u = (u + 0x7FFFu + ((u >> 16) & 1u)) >> 16;   // RNE
  return (unsigned short)u;
}
__device__ __forceinline__ float bf_lo(unsigned int w) { return __uint_as_float(w << 16); }
__device__ __forceinline__ float bf_hi(unsigned int w) { return __uint_as_float(w & 0xFFFF0000u); }

// ---------------- prep: Wt[t][n][k] = bf16(W[t][k][n])  ||  cnt = 0 ----------------
__global__ void k_prep(const float* __restrict__ W, unsigned short* __restrict__ Wt,
                       int* __restrict__ cnt) {
  int bid = blockIdx.x;
  if (bid < 192) {
    int idx = bid * 256 + threadIdx.x;          // 3*128*128 = 49152 elements
    int t = idx >> 14, rem = idx & 16383;
    int n = rem >> 7, k = rem & 127;
    Wt[((size_t)t * C + n) * C + k] = f2bf(W[((size_t)t * C + k) * C + n]);
  } else {
    int i4 = (bid - 192) * 256 + threadIdx.x;   // 12500 int4 = 50000 ints
    if (i4 < N_NODES / 4) ((int4*)cnt)[i4] = make_int4(0, 0, 0, 0);
  }
}

// ---------------- fused bin || mm (R6 post-mortem) ----------------
// R6 showed bin(~40) and mm(~45) run SEQUENTIALLY with disjoint resources (bin:
// device-atomic RTT + L2-local scatter, zero VALU; mm: MFMA+LDS+stream writes) and
// neither saturates a pipe. Fuse with groups-of-8 interleave: group g even -> 8 bin
// blocks, g odd -> 8 mm blocks, so every XCD carries both roles CONCURRENTLY and
// bid&7 == XCD still gives bin its dst-range (R5's L2-locality fix preserved:
// buckets/cnt for range r stay in XCD r's L2, ~1.6MB). The old mixing regression
// (R10-note, 65->89us) was bucket lines bouncing between non-coherent L2s — that
// mechanism is gone with range ownership. If k_bm > 75us, segregation still
// matters -> next: role-per-XCD-group split inside the fused grid.
//
// bin (R5 lesson): dst-range per XCD kills the 16x write amplification
//   (WRITE_SIZE 48.3 -> ~5MB; each bucket line absorbs all its stores in-L2).
// mm (R2 lesson): B from LDS, staged once (L1-thrash at 118us otherwise).
// mm (R1 lesson): A in registers — zero cross-lane reuse, saves 17KB LDS.
__global__ void k_bm(const float* __restrict__ x, const int* __restrict__ node_type,
                     const float* __restrict__ emb, const unsigned short* __restrict__ Wt,
                     unsigned short* __restrict__ xwb,
                     const float* __restrict__ att_src, const float* __restrict__ att_dst,
                     float* __restrict__ a_s, float2* __restrict__ ad_es,
                     const int* __restrict__ ei, const int* __restrict__ etype,
                     int* __restrict__ cnt, int* __restrict__ buckets) {
  __shared__ unsigned short Bs[128][136];   // +8 halfword pad (proven R0 layout)
  const int bid = blockIdx.x;
  const int tid = threadIdx.x;

  const int group = bid >> 3, inb = bid & 7;
  int mm_sub;
  if (group < 512) {
    if ((group & 1) == 0) {
      // ---- bin role: range = inb (== this bid's XCD), slice = group>>1 ----
      const int dlo = inb * DST_PER_XCD, dhi = dlo + DST_PER_XCD;
      const int base = (group >> 1) * EDGES_PER_SLICE;
      for (int i = tid; i < EDGES_PER_SLICE; i += 256) {
        int e = base + i;                            // 256*3125 = 800000 exactly
        int d = ei[N_EDGES + e];                     // coalesced, L2/L3-hot
        if (d >= dlo && d < dhi) {                   // ~1/8 of lanes
          int s = ei[e];
          int t = etype[e];
          int p = atomicAdd(&cnt[d], 1);
          if (p < CAP) buckets[(size_t)d * CAP + p] = t * N_NODES + s;
        }
      }
      return;
    }
    mm_sub = (group >> 1) * 8 + inb;                 // 0..2047
  } else {
    mm_sub = 2048 + (bid - 4096);                    // 2048..2345
  }

  // ---- mm role: one (t, 64-row block) ----
  const int t = mm_sub / GEMM_XB;
  const int rb = mm_sub - t * GEMM_XB;
  const int wid = tid >> 6, lane = tid & 63;
  const int m = lane & 15, quad = lane >> 4;
  const int row0 = rb * 64;
  const unsigned short* Wtt = Wt + (size_t)t * C * C;

  // A fragments in registers: lane (wid,m,quad) owns row wid*16+m,
  // k-chunks {k0i*32 + quad*8 .. +8}. bf16(x + emb[node_type]).
  short8 af[4];
  {
    int arow = row0 + wid * 16 + m;
    bool valid = arow < N_NODES;
    const float* xr = x + (size_t)(valid ? arow : 0) * C;   // row 0 if invalid; stores guarded
    int nt = valid ? node_type[arow] : 0;
    const float* er = emb + nt * C;
#pragma unroll
    for (int k0i = 0; k0i < 4; ++k0i) {
      int cb = k0i * 32 + quad * 8;
      float4 v0 = *(const float4*)(xr + cb);
      float4 v1 = *(const float4*)(xr + cb + 4);
      float4 e0 = *(const float4*)(er + cb);
      float4 e1 = *(const float4*)(er + cb + 4);
      short8 f;
      f[0] = (short)f2bf(v0.x + e0.x);
      f[1] = (short)f2bf(v0.y + e0.y);
      f[2] = (short)f2bf(v0.z + e0.z);
      f[3] = (short)f2bf(v0.w + e0.w);
      f[4] = (short)f2bf(v1.x + e1.x);
      f[5] = (short)f2bf(v1.y + e1.y);
      f[6] = (short)f2bf(v1.z + e1.z);
      f[7] = (short)f2bf(v1.w + e1.w);
      af[k0i] = f;
    }
  }

  // stage B once (32KB, L2-hot: same 96KB Wt read by all 2346 mm blocks)
#pragma unroll
  for (int it = 0; it < 8; ++it) {
    int c = tid + it * 256;
    int n = c >> 4, kc = c & 15;
    *(uint4*)&Bs[n][kc * 8] = *(const uint4*)(Wtt + (size_t)n * C + kc * 8);
  }
  __syncthreads();

  f32x4 acc[8] = {};
#pragma unroll
  for (int k0i = 0; k0i < 4; ++k0i) {
    int k0 = k0i * 32;
#pragma unroll
    for (int j = 0; j < 8; ++j) {
      short8 b = *(const short8*)&Bs[j * 16 + m][k0 + quad * 8];
      acc[j] = __builtin_amdgcn_mfma_f32_16x16x32_bf16(af[k0i], b, acc[j], 0, 0, 0);
    }
  }

  // epilogue: write xw (bf16) + fused attention logits (registers/shuffles only)
  float ps[4] = {}, pd[4] = {};
#pragma unroll
  for (int j = 0; j < 8; ++j) {
    float as = att_src[t * C + j * 16 + m];
    float ad = att_dst[t * C + j * 16 + m];
#pragma unroll
    for (int reg = 0; reg < 4; ++reg) {
      int row = row0 + wid * 16 + quad * 4 + reg;
      float v = acc[j][reg];
      if (row < N_NODES) xwb[((size_t)t * N_NODES + row) * C + j * 16 + m] = f2bf(v);
      ps[reg] += v * as;
      pd[reg] += v * ad;
    }
  }
#pragma unroll
  for (int off = 1; off < 16; off <<= 1) {
#pragma unroll
    for (int reg = 0; reg < 4; ++reg) {
      ps[reg] += __shfl_xor(ps[reg], off);
      pd[reg] += __shfl_xor(pd[reg], off);
    }
  }
  if (m == 0) {
#pragma unroll
    for (int reg = 0; reg < 4; ++reg) {
      int row = row0 + wid * 16 + quad * 4 + reg;
      if (row < N_NODES) {
        int idx = t * N_NODES + row;
        a_s[idx] = ps[reg];
        ad_es[idx] = make_float2(pd[reg], leaky(ps[reg] + pd[reg]));  // {a_d, e_self}
      }
    }
  }
}

// ---------------- per node (1 wave): w per lane, denom via wave-reduce, out = self+bias+sum coef*xw ----------------
// Serial loop uses wave-uniform (readfirstlane) bucket-row loads + LDS coefficient
// broadcast instead of 2 ds_bpermute per edge.
__global__ void k_gather(const int* __restrict__ cnt, const int* __restrict__ buckets,
                         const unsigned short* __restrict__ xwb,
                         const float* __restrict__ a_s, const float2* __restrict__ ad_es,
                         const float* __restrict__ bias, float* __restrict__ out) {
  __shared__ float wcs[4][64];
  int wid = threadIdx.x >> 6;
  int lane = threadIdx.x & 63;
  int i = blockIdx.x * 4 + wid;                       // grid covers N exactly (12500*4)
  int iu = __builtin_amdgcn_readfirstlane(i);         // wave-uniform node id
  const int* __restrict__ brow = buckets + (size_t)iu * CAP;
  int n = cnt[iu];
  if (n > CAP) n = CAP;

  int idxl = 0;
  if (lane < n) idxl = brow[lane];                    // coalesced 256B wave load
  int tl = idxl >= 2 * N_NODES ? 2 : (idxl >= N_NODES ? 1 : 0);
  float as = a_s[idxl];                               // random 4B, L2-resident (600 KB)
  float2 am = ad_es[tl * N_NODES + iu];               // 3 distinct addrs per wave
  float wl = (lane < n) ? __expf(leaky(as + am.x) - am.y) : 0.f;

  // per-type denominators: butterfly-reduce w by type
  float s0 = tl == 0 ? wl : 0.f;
  float s1 = tl == 1 ? wl : 0.f;
  float s2 = tl == 2 ? wl : 0.f;
#pragma unroll
  for (int off = 1; off < 64; off <<= 1) {
    s0 += __shfl_xor(s0, off);
    s1 += __shfl_xor(s1, off);
    s2 += __shfl_xor(s2, off);
  }
  float inv3[NT] = {1.f / (s0 + 1.f), 1.f / (s1 + 1.f), 1.f / (s2 + 1.f)};  // w_self == 1
  wcs[wid][lane] = wl * inv3[tl];   // premultiplied coefficient, broadcast via LDS

  // self-loop (coef = inv3[t]) + bias
  float acc0 = 0.f, acc1 = 0.f;   // cols 2*lane, 2*lane+1
#pragma unroll
  for (int t = 0; t < NT; ++t) {
    int idx = t * N_NODES + iu;
    float coef = inv3[t];
    unsigned int w = ((const unsigned int*)(xwb + (size_t)idx * C))[lane];
    float2 b2 = ((const float2*)(bias + t * C))[lane];
    acc0 += coef * bf_lo(w) + b2.x;
    acc1 += coef * bf_hi(w) + b2.y;
  }

  const unsigned int* xwu = (const unsigned int*)xwb;
  int j = 0;
  for (; j + 16 <= n; j += 16) {   // 16-way MLP
    float ac0 = 0.f, ac1 = 0.f;
#pragma unroll
    for (int k = 0; k < 16; ++k) {
      int idx = brow[j + k];          // wave-uniform load (L1-hot line)
      float c = wcs[wid][j + k];      // LDS broadcast, conflict-free
      unsigned int v = xwu[(size_t)idx * (C / 2) + lane];
      ac0 += c * bf_lo(v);
      ac1 += c * bf_hi(v);
    }
    acc0 += ac0; acc1 += ac1;
  }
  for (; j + 8 <= n; j += 8) {     // 8-way MLP
    float ac0 = 0.f, ac1 = 0.f;
#pragma unroll
    for (int k = 0; k < 8; ++k) {
      int idx = brow[j + k];
      float c = wcs[wid][j + k];
      unsigned int v = xwu[(size_t)idx * (C / 2) + lane];
      ac0 += c * bf_lo(v);
      ac1 += c * bf_hi(v);
    }
    acc0 += ac0; acc1 += ac1;
  }
  for (; j < n; ++j) {
    int idx = brow[j];
    float c = wcs[wid][j];
    unsigned int v = xwu[(size_t)idx * (C / 2) + lane];
    acc0 += c * bf_lo(v);
    acc1 += c * bf_hi(v);
  }
  ((float2*)(out + (size_t)iu * C))[lane] = make_float2(acc0, acc1);
}

extern "C" void kernel_launch(void* const* d_in, const int* in_sizes, int n_in,
                              void* d_out, int out_size, void* d_ws, size_t ws_size,
                              hipStream_t stream) {
  const float* x       = (const float*)d_in[0];
  const int* edge_idx  = (const int*)d_in[1];
  const int* edge_type = (const int*)d_in[2];
  const int* node_type = (const int*)d_in[3];
  const float* emb     = (const float*)d_in[4];
  const float* W       = (const float*)d_in[5];
  const float* att_src = (const float*)d_in[6];
  const float* att_dst = (const float*)d_in[7];
  const float* bias    = (const float*)d_in[8];
  float* out = (float*)d_out;

  // workspace layout (~53 MB)
  unsigned short* xwb = (unsigned short*)d_ws;                 // 3*N*C bf16 (38.4 MB)
  unsigned short* Wt  = xwb + (size_t)NT * N_NODES * C;        // 3*C*C bf16 (96 KB)
  float*  a_s   = (float*)(Wt + (size_t)NT * C * C);           // 3*N (600 KB)
  float2* ad_es = (float2*)(a_s + (size_t)NT * N_NODES);       // 3*N float2 (1.2 MB)
  int*    cnt   = (int*)(ad_es + (size_t)NT * N_NODES);        // N ints
  int*    buckets = (int*)(cnt + N_NODES);                     // N*CAP int (12.8 MB)

  k_prep<<<192 + 49, 256, 0, stream>>>(W, Wt, cnt);

  k_bm<<<BM_GRID, 256, 0, stream>>>(x, node_type, emb, Wt, xwb, att_src, att_dst,
                                    a_s, ad_es, edge_idx, edge_type, cnt, buckets);

  k_gather<<<N_NODES / 4, 256, 0, stream>>>(cnt, buckets, xwb, a_s, ad_es, bias, out);
}

// Round 8
// 173.304 us; speedup vs baseline: 1.2057x; 1.2057x over previous
//
#include <hip/hip_runtime.h>
#include <math.h>

#define N_NODES 50000
#define N_EDGES 800000
#define C 128
#define NT 3
#define NEG 0.2f
#define CAP 64   // max in-edges per node kept (Poisson(16): max observed degree ~45)

#define GEMM_XB 782          // ceil(N_NODES/64)
#define NCHUNK 782           // edge chunks of 1024 (last partial: 256)

typedef __attribute__((ext_vector_type(8))) short short8;   // 8 bf16 = 4 VGPRs
typedef __attribute__((ext_vector_type(4))) float f32x4;

__device__ __forceinline__ float leaky(float v) { return v > 0.f ? v : NEG * v; }

__device__ __forceinline__ unsigned short f2bf(float f) {
  unsigned int u = __float_as_uint(f);
  u = (u + 0x7FFFu + ((u >> 16) & 1u)) >> 16;   // RNE
  return (unsigned short)u;
}
__device__ __forceinline__ float bf_lo(unsigned int w) { return __uint_as_float(w << 16); }
__device__ __forceinline__ float bf_hi(unsigned int w) { return __uint_as_float(w & 0xFFFF0000u); }

// ---------------- prep: Wt[t][n][k] = bf16(W[t][k][n])  ||  cnt = 0 ----------------
__global__ void k_prep(const float* __restrict__ W, unsigned short* __restrict__ Wt,
                       int* __restrict__ cnt) {
  int bid = blockIdx.x;
  if (bid < 192) {
    int idx = bid * 256 + threadIdx.x;          // 3*128*128 = 49152 elements
    int t = idx >> 14, rem = idx & 16383;
    int n = rem >> 7, k = rem & 127;
    Wt[((size_t)t * C + n) * C + k] = f2bf(W[((size_t)t * C + k) * C + n]);
  } else {
    int i4 = (bid - 192) * 256 + threadIdx.x;   // 12500 int4 = 50000 ints
    if (i4 < N_NODES / 4) ((int4*)cnt)[i4] = make_int4(0, 0, 0, 0);
  }
}

// ---------------- fused SEGREGATED bin || mm (R7 post-mortem) ----------------
// R7 (mixed roles per XCD) = 90us ≈ serial sum: mm's streaming evicted bucket
// lines from the shared L2 -> R5's write-amp fix reverted (WRITE 78MB, FETCH +28MB
// bucket RMW). R0 (segregated: bin odd-bid XCDs / mm even-bid XCDs) = 65us for the
// SAME total work -> segregation is what makes overlap free (bin owns 4 L2s, mm
// owns the other 4; they couple only at fabric/HBM).
// This round = R0's grid + three proven upgrades:
//  1. bin partitioned WITHIN segregation: class c=(bid>>1)&3 owns dst range
//     [c*12500,+12500) (3.2MB buckets+cnt fits that XCD's L2, no mm traffic in it)
//     -> write-amp gone (R5 lesson) without R7's eviction (segregation kept).
//  2. mm: A in registers, loaded ONCE per block (R1 lesson, -17KB LDS -> 4 blk/CU)
//     and reused across the t-loop (R3 reloaded A 3x).
//  3. B from LDS staged per t (R2 lesson), 2-barrier switch (R0 pattern).
// Failure rule: k_bm > 70us -> combo adds nothing over R0's 65; pivot to gather.
__global__ void k_bm(const float* __restrict__ x, const int* __restrict__ node_type,
                     const float* __restrict__ emb, const unsigned short* __restrict__ Wt,
                     unsigned short* __restrict__ xwb,
                     const float* __restrict__ att_src, const float* __restrict__ att_dst,
                     float* __restrict__ a_s, float2* __restrict__ ad_es,
                     const int* __restrict__ ei, const int* __restrict__ etype,
                     int* __restrict__ cnt, int* __restrict__ buckets) {
  __shared__ unsigned short Bs[128][136];   // +8 halfword pad (proven R0 layout)
  const int bid = blockIdx.x;
  const int tid = threadIdx.x;

  if (bid & 1) {
    // ---- bin role (XCDs 1,3,5,7): class owns contiguous 12500-dst range ----
    const int j = bid >> 1;                  // 0..781
    const int c = j & 3;                     // == ((bid%8)>>1): stable per XCD
    const int i = j >> 2;                    // index within class
    const int n_c = (c < 2) ? 196 : 195;     // blocks in this class
    const int dlo = c * 12500, dhi = dlo + 12500;
    for (int cc = i; cc < NCHUNK; cc += n_c) {       // strided chunk coverage
      int e0 = cc * 1024 + tid * 4;
      if (e0 + 4 <= N_EDGES) {               // N_EDGES%4==0: full quad or nothing
        int4 s4 = *(const int4*)(ei + e0);
        int4 d4 = *(const int4*)(ei + N_EDGES + e0);
        int4 t4 = *(const int4*)(etype + e0);
        if (d4.x >= dlo && d4.x < dhi) {
          int p = atomicAdd(&cnt[d4.x], 1);
          if (p < CAP) buckets[(size_t)d4.x * CAP + p] = t4.x * N_NODES + s4.x;
        }
        if (d4.y >= dlo && d4.y < dhi) {
          int p = atomicAdd(&cnt[d4.y], 1);
          if (p < CAP) buckets[(size_t)d4.y * CAP + p] = t4.y * N_NODES + s4.y;
        }
        if (d4.z >= dlo && d4.z < dhi) {
          int p = atomicAdd(&cnt[d4.z], 1);
          if (p < CAP) buckets[(size_t)d4.z * CAP + p] = t4.z * N_NODES + s4.z;
        }
        if (d4.w >= dlo && d4.w < dhi) {
          int p = atomicAdd(&cnt[d4.w], 1);
          if (p < CAP) buckets[(size_t)d4.w * CAP + p] = t4.w * N_NODES + s4.w;
        }
      }
    }
    return;
  }

  // ---- mm role (XCDs 0,2,4,6): one 64-row block, t-loop, A in regs once ----
  const int rb = bid >> 1;                   // 0..781
  const int wid = tid >> 6, lane = tid & 63;
  const int m = lane & 15, quad = lane >> 4;
  const int row0 = rb * 64;

  // A fragments in registers, t-invariant: lane (wid,m,quad) owns row wid*16+m,
  // k-chunks {k0i*32 + quad*8 .. +8}. bf16(x + emb[node_type]).
  short8 af[4];
  {
    int arow = row0 + wid * 16 + m;
    bool valid = arow < N_NODES;
    const float* xr = x + (size_t)(valid ? arow : 0) * C;   // row 0 if invalid; stores guarded
    int nt = valid ? node_type[arow] : 0;
    const float* er = emb + nt * C;
#pragma unroll
    for (int k0i = 0; k0i < 4; ++k0i) {
      int cb = k0i * 32 + quad * 8;
      float4 v0 = *(const float4*)(xr + cb);
      float4 v1 = *(const float4*)(xr + cb + 4);
      float4 e0 = *(const float4*)(er + cb);
      float4 e1 = *(const float4*)(er + cb + 4);
      short8 f;
      f[0] = (short)f2bf(v0.x + e0.x);
      f[1] = (short)f2bf(v0.y + e0.y);
      f[2] = (short)f2bf(v0.z + e0.z);
      f[3] = (short)f2bf(v0.w + e0.w);
      f[4] = (short)f2bf(v1.x + e1.x);
      f[5] = (short)f2bf(v1.y + e1.y);
      f[6] = (short)f2bf(v1.z + e1.z);
      f[7] = (short)f2bf(v1.w + e1.w);
      af[k0i] = f;
    }
  }

  // stage B for t=0 (32KB, L2-hot: same 96KB Wt read by all mm blocks)
#pragma unroll
  for (int it = 0; it < 8; ++it) {
    int c = tid + it * 256;
    int n = c >> 4, kc = c & 15;
    *(uint4*)&Bs[n][kc * 8] = *(const uint4*)(Wt + (size_t)n * C + kc * 8);
  }
  __syncthreads();

  for (int t = 0; t < NT; ++t) {
    f32x4 acc[8] = {};
#pragma unroll
    for (int k0i = 0; k0i < 4; ++k0i) {
      int k0 = k0i * 32;
#pragma unroll
      for (int j = 0; j < 8; ++j) {
        short8 b = *(const short8*)&Bs[j * 16 + m][k0 + quad * 8];
        acc[j] = __builtin_amdgcn_mfma_f32_16x16x32_bf16(af[k0i], b, acc[j], 0, 0, 0);
      }
    }

    // epilogue: write xw (bf16) + fused attention logits (registers/shuffles only)
    float ps[4] = {}, pd[4] = {};
#pragma unroll
    for (int j = 0; j < 8; ++j) {
      float as = att_src[t * C + j * 16 + m];
      float ad = att_dst[t * C + j * 16 + m];
#pragma unroll
      for (int reg = 0; reg < 4; ++reg) {
        int row = row0 + wid * 16 + quad * 4 + reg;
        float v = acc[j][reg];
        if (row < N_NODES) xwb[((size_t)t * N_NODES + row) * C + j * 16 + m] = f2bf(v);
        ps[reg] += v * as;
        pd[reg] += v * ad;
      }
    }
#pragma unroll
    for (int off = 1; off < 16; off <<= 1) {
#pragma unroll
      for (int reg = 0; reg < 4; ++reg) {
        ps[reg] += __shfl_xor(ps[reg], off);
        pd[reg] += __shfl_xor(pd[reg], off);
      }
    }
    if (m == 0) {
#pragma unroll
      for (int reg = 0; reg < 4; ++reg) {
        int row = row0 + wid * 16 + quad * 4 + reg;
        if (row < N_NODES) {
          int idx = t * N_NODES + row;
          a_s[idx] = ps[reg];
          ad_es[idx] = make_float2(pd[reg], leaky(ps[reg] + pd[reg]));  // {a_d, e_self}
        }
      }
    }

    if (t + 1 < NT) {
      __syncthreads();          // all waves done reading Bs
      const unsigned short* Wtt = Wt + (size_t)(t + 1) * C * C;
#pragma unroll
      for (int it = 0; it < 8; ++it) {
        int c = tid + it * 256;
        int n = c >> 4, kc = c & 15;
        *(uint4*)&Bs[n][kc * 8] = *(const uint4*)(Wtt + (size_t)n * C + kc * 8);
      }
      __syncthreads();
    }
  }
}

// ---------------- per node (1 wave): w per lane, denom via wave-reduce, out = self+bias+sum coef*xw ----------------
// Serial loop uses wave-uniform (readfirstlane) bucket-row loads + LDS coefficient
// broadcast instead of 2 ds_bpermute per edge.
__global__ void k_gather(const int* __restrict__ cnt, const int* __restrict__ buckets,
                         const unsigned short* __restrict__ xwb,
                         const float* __restrict__ a_s, const float2* __restrict__ ad_es,
                         const float* __restrict__ bias, float* __restrict__ out) {
  __shared__ float wcs[4][64];
  int wid = threadIdx.x >> 6;
  int lane = threadIdx.x & 63;
  int i = blockIdx.x * 4 + wid;                       // grid covers N exactly (12500*4)
  int iu = __builtin_amdgcn_readfirstlane(i);         // wave-uniform node id
  const int* __restrict__ brow = buckets + (size_t)iu * CAP;
  int n = cnt[iu];
  if (n > CAP) n = CAP;

  int idxl = 0;
  if (lane < n) idxl = brow[lane];                    // coalesced 256B wave load
  int tl = idxl >= 2 * N_NODES ? 2 : (idxl >= N_NODES ? 1 : 0);
  float as = a_s[idxl];                               // random 4B, L2-resident (600 KB)
  float2 am = ad_es[tl * N_NODES + iu];               // 3 distinct addrs per wave
  float wl = (lane < n) ? __expf(leaky(as + am.x) - am.y) : 0.f;

  // per-type denominators: butterfly-reduce w by type
  float s0 = tl == 0 ? wl : 0.f;
  float s1 = tl == 1 ? wl : 0.f;
  float s2 = tl == 2 ? wl : 0.f;
#pragma unroll
  for (int off = 1; off < 64; off <<= 1) {
    s0 += __shfl_xor(s0, off);
    s1 += __shfl_xor(s1, off);
    s2 += __shfl_xor(s2, off);
  }
  float inv3[NT] = {1.f / (s0 + 1.f), 1.f / (s1 + 1.f), 1.f / (s2 + 1.f)};  // w_self == 1
  wcs[wid][lane] = wl * inv3[tl];   // premultiplied coefficient, broadcast via LDS

  // self-loop (coef = inv3[t]) + bias
  float acc0 = 0.f, acc1 = 0.f;   // cols 2*lane, 2*lane+1
#pragma unroll
  for (int t = 0; t < NT; ++t) {
    int idx = t * N_NODES + iu;
    float coef = inv3[t];
    unsigned int w = ((const unsigned int*)(xwb + (size_t)idx * C))[lane];
    float2 b2 = ((const float2*)(bias + t * C))[lane];
    acc0 += coef * bf_lo(w) + b2.x;
    acc1 += coef * bf_hi(w) + b2.y;
  }

  const unsigned int* xwu = (const unsigned int*)xwb;
  int j = 0;
  for (; j + 16 <= n; j += 16) {   // 16-way MLP
    float ac0 = 0.f, ac1 = 0.f;
#pragma unroll
    for (int k = 0; k < 16; ++k) {
      int idx = brow[j + k];          // wave-uniform load (L1-hot line)
      float c = wcs[wid][j + k];      // LDS broadcast, conflict-free
      unsigned int v = xwu[(size_t)idx * (C / 2) + lane];
      ac0 += c * bf_lo(v);
      ac1 += c * bf_hi(v);
    }
    acc0 += ac0; acc1 += ac1;
  }
  for (; j + 8 <= n; j += 8) {     // 8-way MLP
    float ac0 = 0.f, ac1 = 0.f;
#pragma unroll
    for (int k = 0; k < 8; ++k) {
      int idx = brow[j + k];
      float c = wcs[wid][j + k];
      unsigned int v = xwu[(size_t)idx * (C / 2) + lane];
      ac0 += c * bf_lo(v);
      ac1 += c * bf_hi(v);
    }
    acc0 += ac0; acc1 += ac1;
  }
  for (; j < n; ++j) {
    int idx = brow[j];
    float c = wcs[wid][j];
    unsigned int v = xwu[(size_t)idx * (C / 2) + lane];
    acc0 += c * bf_lo(v);
    acc1 += c * bf_hi(v);
  }
  ((float2*)(out + (size_t)iu * C))[lane] = make_float2(acc0, acc1);
}

extern "C" void kernel_launch(void* const* d_in, const int* in_sizes, int n_in,
                              void* d_out, int out_size, void* d_ws, size_t ws_size,
                              hipStream_t stream) {
  const float* x       = (const float*)d_in[0];
  const int* edge_idx  = (const int*)d_in[1];
  const int* edge_type = (const int*)d_in[2];
  const int* node_type = (const int*)d_in[3];
  const float* emb     = (const float*)d_in[4];
  const float* W       = (const float*)d_in[5];
  const float* att_src = (const float*)d_in[6];
  const float* att_dst = (const float*)d_in[7];
  const float* bias    = (const float*)d_in[8];
  float* out = (float*)d_out;

  // workspace layout (~53 MB)
  unsigned short* xwb = (unsigned short*)d_ws;                 // 3*N*C bf16 (38.4 MB)
  unsigned short* Wt  = xwb + (size_t)NT * N_NODES * C;        // 3*C*C bf16 (96 KB)
  float*  a_s   = (float*)(Wt + (size_t)NT * C * C);           // 3*N (600 KB)
  float2* ad_es = (float2*)(a_s + (size_t)NT * N_NODES);       // 3*N float2 (1.2 MB)
  int*    cnt   = (int*)(ad_es + (size_t)NT * N_NODES);        // N ints
  int*    buckets = (int*)(cnt + N_NODES);                     // N*CAP int (12.8 MB)

  k_prep<<<192 + 49, 256, 0, stream>>>(W, Wt, cnt);

  k_bm<<<2 * GEMM_XB, 256, 0, stream>>>(x, node_type, emb, Wt, xwb, att_src, att_dst,
                                        a_s, ad_es, edge_idx, edge_type, cnt, buckets);

  k_gather<<<N_NODES / 4, 256, 0, stream>>>(cnt, buckets, xwb, a_s, ad_es, bias, out);
}